// Round 13
// baseline (966.481 us; speedup 1.0000x reference)
//
#include <hip/hip_runtime.h>

#define HDIM 128
#define GDIM 512   // 4H
#define TSTEPS 512
#define DDIM 12
#define BATCH 1024
#define RROWS 4                  // batch rows per block
#define NBLK (BATCH / RROWS)     // 256 blocks -> 1 per CU
#define NTHR 512                 // 8 waves

typedef _Float16 half8 __attribute__((ext_vector_type(8)));
typedef float f32x4 __attribute__((ext_vector_type(4)));

#define MFMA16 __builtin_amdgcn_mfma_f32_16x16x32_f16

__device__ __forceinline__ float fsig(float x) {
  float t = __expf(-x);
  return __builtin_amdgcn_rcpf(1.0f + t);
}
__device__ __forceinline__ float ftanh_(float x) {
  float t = __expf(2.0f * x);
  return 1.0f - 2.0f * __builtin_amdgcn_rcpf(t + 1.0f);
}

__device__ __forceinline__ half8 ldfrag8(const float* p) {
  half8 h;
#pragma unroll
  for (int j = 0; j < 8; ++j) h[j] = (_Float16)p[j];
  return h;
}

// REGISTER-BUDGET FIX (round 12 post-mortem): the RA's occupancy target is
// LDS-aware. At 67 KB LDS, TWO 512-thr workgroups fit per CU (<=81920 B each),
// so the allocator budgets 128 VGPR for 4 waves/EU and spills the 192-VGPR
// weight set (WRITE_SIZE 88 MB, rounds 3/6/12) regardless of waves_per_eu
// hints. Padding LDS past 80 KB (wih0s lane-dim 64->96, pad never indexed)
// makes 1 WG/CU the compiler-visible maximum -> 8 waves -> 2 waves/EU ->
// 256-VGPR budget from the RA's own occupancy math. Runtime occupancy is
// unchanged (grid is already 1 block/CU).
// Weights MUST live in registers: 3 matrices x 512x128 x fp16 = 384 KB/CU,
// > 160 KB LDS, and > the 256 KB register file available at a 128-VGPR cap.
__global__
__attribute__((amdgpu_flat_work_group_size(NTHR, NTHR)))
__attribute__((amdgpu_waves_per_eu(2, 2)))
void lstm_fused_kernel(
    const float* __restrict__ x,
    const float* __restrict__ Wih0, const float* __restrict__ Whh0,
    const float* __restrict__ bih0, const float* __restrict__ bhh0,
    const float* __restrict__ Wih1, const float* __restrict__ Whh1,
    const float* __restrict__ bih1, const float* __restrict__ bhh1,
    const float* __restrict__ W1, const float* __restrict__ b1,
    const float* __restrict__ W2, const float* __restrict__ b2,
    const float* __restrict__ W3, const float* __restrict__ b3,
    float* __restrict__ out)
{
  __shared__ _Float16 h1b[2][16 * HDIM];   // 8 KB
  __shared__ _Float16 h2b[2][16 * HDIM];   // 8 KB
  __shared__ _Float16 xsb[8][16 * 32];     // 8 KB
  __shared__ float rd[8][4][16][4];        // 8 KB  per-wave gate redistribution
  __shared__ _Float16 wih0s[8][4][96][8];  // 48 KB: lane-dim padded 64->96 (LDS>80KB trick); only [..][l<64][..] used
  __shared__ float z1s[4][64];
  __shared__ float z2s[4][32];

  const int tid = threadIdx.x;
  const int l  = tid & 63;
  const int w  = tid >> 6;          // wave 0..7
  const int fr = l & 15;            // fragment row (A) / B-col offset
  const int fk = l >> 4;            // k-group 0..3
  const int swzA = (fr & 7) << 3;   // XOR swizzle in f16 elems
  const int c = l & 15;             // redistributed h-col offset
  const int r = l >> 4;             // redistributed batch row 0..3
  const int rowbase = blockIdx.x * RROWS;
  const int hcol = w * 16 + c;
  const int hwidx = (r * HDIM + hcol) ^ (r << 3);

  // ---- zero LDS h buffers and x buffer (pad rows/cols must stay 0) ----
  {
    _Float16* f1 = &h1b[0][0];
    _Float16* f2 = &h2b[0][0];
    _Float16* f3 = &xsb[0][0];
    for (int i = tid; i < 2 * 16 * HDIM; i += NTHR) { f1[i] = (_Float16)0.0f; f2[i] = (_Float16)0.0f; }
    for (int i = tid; i < 8 * 16 * 32; i += NTHR) f3[i] = (_Float16)0.0f;
  }

  // ---- preload weight fragments: Whh0/Wih1/Whh1 in registers (192 VGPR),
  //      Wih0 (with folded layer-0 bias) staged to LDS ----
  half8 whh0f[4][4], wih1f[4][4], whh1f[4][4];
  float bias1f[4];
#pragma unroll
  for (int tt = 0; tt < 4; ++tt) {
    const int gr = (w + tt * 8) * 16 + fr;       // gate row in [0,512)
    const float* pr0 = Whh0 + gr * HDIM;
    const float* pr1 = Wih1 + gr * HDIM;
    const float* pr2 = Whh1 + gr * HDIM;
#pragma unroll
    for (int kt = 0; kt < 4; ++kt) {
      whh0f[tt][kt] = ldfrag8(pr0 + kt * 32 + fk * 8);
      wih1f[tt][kt] = ldfrag8(pr1 + kt * 32 + fk * 8);
      whh1f[tt][kt] = ldfrag8(pr2 + kt * 32 + fk * 8);
    }
    half8 hf;
#pragma unroll
    for (int j = 0; j < 8; ++j) {
      const int k = fk * 8 + j;
      float v = 0.0f;
      if (k < DDIM) v = Wih0[gr * DDIM + k];
      else if (k == DDIM) v = bih0[gr] + bhh0[gr];
      hf[j] = (_Float16)v;
    }
    *(half8*)&wih0s[w][tt][l][0] = hf;
    const int gc = tt * HDIM + hcol;
    bias1f[tt] = bih1[gc] + bhh1[gc];
  }

  const f32x4 zf = {0.0f, 0.0f, 0.0f, 0.0f};
  float c0v = 0.0f, c1v = 0.0f;
  int p = 0;

  for (int t = 0; t < TSTEPS; ++t) {
    // ---- restage x chunk (8 timesteps) every 8 steps ----
    if ((t & 7) == 0) {
      if (tid < 384) {
        const int rr = tid / 96, rem = tid % 96;
        const int tts = rem / 12, d = rem % 12;
        const float v = x[(size_t)(rowbase + rr) * (TSTEPS * DDIM) + (size_t)(t + tts) * DDIM + d];
        xsb[tts][(rr * 32 + d) ^ (rr << 3)] = (_Float16)v;
      } else if (tid < 416) {
        const int q = tid - 384;
        const int rr = q >> 3, tts = q & 7;
        xsb[tts][(rr * 32 + DDIM) ^ (rr << 3)] = (_Float16)1.0f;  // bias-one col
      }
      __syncthreads();
    }

    // ================= phase A : layer 0 =================
    half8 xa = *(const half8*)&xsb[t & 7][(fr * 32 + fk * 8) ^ swzA];
    f32x4 a0, a1, a2, a3;
    {
      half8 w0 = *(const half8*)&wih0s[w][0][l][0];
      half8 w1 = *(const half8*)&wih0s[w][1][l][0];
      half8 w2 = *(const half8*)&wih0s[w][2][l][0];
      half8 w3 = *(const half8*)&wih0s[w][3][l][0];
      a0 = MFMA16(xa, w0, zf, 0, 0, 0);
      a1 = MFMA16(xa, w1, zf, 0, 0, 0);
      a2 = MFMA16(xa, w2, zf, 0, 0, 0);
      a3 = MFMA16(xa, w3, zf, 0, 0, 0);
    }
#pragma unroll
    for (int kt = 0; kt < 4; ++kt) {
      half8 ha = *(const half8*)&h1b[p][(fr * HDIM + kt * 32 + fk * 8) ^ swzA];
      a0 = MFMA16(ha, whh0f[0][kt], a0, 0, 0, 0);
      a1 = MFMA16(ha, whh0f[1][kt], a1, 0, 0, 0);
      a2 = MFMA16(ha, whh0f[2][kt], a2, 0, 0, 0);
      a3 = MFMA16(ha, whh0f[3][kt], a3, 0, 0, 0);
    }
    if (l < 16) {
      *(f32x4*)&rd[w][0][l][0] = a0;
      *(f32x4*)&rd[w][1][l][0] = a1;
      *(f32x4*)&rd[w][2][l][0] = a2;
      *(f32x4*)&rd[w][3][l][0] = a3;
    }
    {
      const float gi = rd[w][0][c][r];
      const float gf = rd[w][1][c][r];
      const float gg = rd[w][2][c][r];
      const float go = rd[w][3][c][r];
      const float iv = fsig(gi), fv = fsig(gf), gv = ftanh_(gg), ov = fsig(go);
      c0v = fv * c0v + iv * gv;
      const float h1v = ov * ftanh_(c0v);
      h1b[p ^ 1][hwidx] = (_Float16)h1v;
    }
    __syncthreads();  // B1: h1(t) visible; sole barrier per step

    // ================= phase B : layer 1 =================
    f32x4 d0, d1, d2, d3;
    {
      const int fo0 = (fr * HDIM + fk * 8) ^ swzA;
      half8 p1 = *(const half8*)&h1b[p ^ 1][fo0];
      half8 p2 = *(const half8*)&h2b[p][fo0];
      d0 = MFMA16(p1, wih1f[0][0], zf, 0, 0, 0);
      d1 = MFMA16(p1, wih1f[1][0], zf, 0, 0, 0);
      d2 = MFMA16(p1, wih1f[2][0], zf, 0, 0, 0);
      d3 = MFMA16(p1, wih1f[3][0], zf, 0, 0, 0);
      d0 = MFMA16(p2, whh1f[0][0], d0, 0, 0, 0);
      d1 = MFMA16(p2, whh1f[1][0], d1, 0, 0, 0);
      d2 = MFMA16(p2, whh1f[2][0], d2, 0, 0, 0);
      d3 = MFMA16(p2, whh1f[3][0], d3, 0, 0, 0);
    }
#pragma unroll
    for (int kt = 1; kt < 4; ++kt) {
      const int fo = (fr * HDIM + kt * 32 + fk * 8) ^ swzA;
      half8 p1 = *(const half8*)&h1b[p ^ 1][fo];
      half8 p2 = *(const half8*)&h2b[p][fo];
      d0 = MFMA16(p1, wih1f[0][kt], d0, 0, 0, 0);
      d1 = MFMA16(p1, wih1f[1][kt], d1, 0, 0, 0);
      d2 = MFMA16(p1, wih1f[2][kt], d2, 0, 0, 0);
      d3 = MFMA16(p1, wih1f[3][kt], d3, 0, 0, 0);
      d0 = MFMA16(p2, whh1f[0][kt], d0, 0, 0, 0);
      d1 = MFMA16(p2, whh1f[1][kt], d1, 0, 0, 0);
      d2 = MFMA16(p2, whh1f[2][kt], d2, 0, 0, 0);
      d3 = MFMA16(p2, whh1f[3][kt], d3, 0, 0, 0);
    }
    if (l < 16) {
      *(f32x4*)&rd[w][0][l][0] = d0;
      *(f32x4*)&rd[w][1][l][0] = d1;
      *(f32x4*)&rd[w][2][l][0] = d2;
      *(f32x4*)&rd[w][3][l][0] = d3;
    }
    {
      const float gi = rd[w][0][c][r] + bias1f[0];
      const float gf = rd[w][1][c][r] + bias1f[1];
      const float gg = rd[w][2][c][r] + bias1f[2];
      const float go = rd[w][3][c][r] + bias1f[3];
      const float iv = fsig(gi), fv = fsig(gf), gv = ftanh_(gg), ov = fsig(go);
      c1v = fv * c1v + iv * gv;
      const float h2v = ov * ftanh_(c1v);
      h2b[p ^ 1][hwidx] = (_Float16)h2v;
    }
    // no second barrier: phaseA(t+1) touches h1b[p]/xsb only (reads all pre-B1);
    // h2b[p^1] readers are in phaseB(t+1), ordered by B1(t+1).
    p ^= 1;
  }

  __syncthreads();  // h2b[p] writes visible for the MLP head

  // ================= MLP head =================
  if (tid < 256) {
    const int rr = tid >> 6, j = tid & 63;
    float s = b1[j];
    const float* wrow = W1 + j * HDIM;
#pragma unroll 4
    for (int k = 0; k < HDIM; ++k)
      s += (float)h2b[p][(rr * HDIM + k) ^ (rr << 3)] * wrow[k];
    z1s[rr][j] = fmaxf(s, 0.0f);
  }
  __syncthreads();
  if (tid < 128) {
    const int rr = tid >> 5, j = tid & 31;
    float s = b2[j];
    const float* wrow = W2 + j * 64;
#pragma unroll 4
    for (int k = 0; k < 64; ++k) s += z1s[rr][k] * wrow[k];
    z2s[rr][j] = fmaxf(s, 0.0f);
  }
  __syncthreads();
  if (tid < 8) {
    const int rr = tid >> 1, j = tid & 1;
    float s = b3[j];
    const float* wrow = W3 + j * 32;
#pragma unroll
    for (int k = 0; k < 32; ++k) s += z2s[rr][k] * wrow[k];
    out[(rowbase + rr) * 2 + j] = s;
  }
}

extern "C" void kernel_launch(void* const* d_in, const int* in_sizes, int n_in,
                              void* d_out, int out_size, void* d_ws, size_t ws_size,
                              hipStream_t stream) {
  (void)in_sizes; (void)n_in; (void)out_size; (void)d_ws; (void)ws_size;
  lstm_fused_kernel<<<NBLK, NTHR, 0, stream>>>(
      (const float*)d_in[0],
      (const float*)d_in[1], (const float*)d_in[2],
      (const float*)d_in[3], (const float*)d_in[4],
      (const float*)d_in[5], (const float*)d_in[6],
      (const float*)d_in[7], (const float*)d_in[8],
      (const float*)d_in[9], (const float*)d_in[10],
      (const float*)d_in[11], (const float*)d_in[12],
      (const float*)d_in[13], (const float*)d_in[14],
      (float*)d_out);
}